// Round 1
// baseline (216.165 us; speedup 1.0000x reference)
//
#include <hip/hip_runtime.h>

// Problem constants (from reference): B=32, N=25200, C=85
constexpr int B_ = 32;
constexpr int N_ = 25200;
constexpr int C_ = 85;
constexpr int NC = N_ * C_;          // 2,142,000  (divisible by 4)
constexpr int NC4 = NC / 4;          // 535,500 float4s per image per modality
constexpr int OUT_IMG = 2 * NC;      // 4,284,000  (divisible by 4)

__global__ __launch_bounds__(256) void modal_ense_kernel(
    const float* __restrict__ vis,
    const float* __restrict__ lwir,
    const float* __restrict__ aware,
    float* __restrict__ out)
{
    const unsigned total = (unsigned)B_ * NC4 * 2u;   // 34,272,000 float4 tasks
    unsigned i = blockIdx.x * blockDim.x + threadIdx.x;
    const unsigned stride = gridDim.x * blockDim.x;

    const unsigned visTasks = (unsigned)B_ * NC4;

    for (; i < total; i += stride) {
        if (i < visTasks) {
            // ---- visible half: scale cols >= 5 by aware[b] ----
            unsigned b  = i / (unsigned)NC4;          // magic-mul
            unsigned m4 = i - b * (unsigned)NC4;
            unsigned m  = m4 * 4u;                    // flat elem offset within image
            unsigned c  = m % (unsigned)C_;           // column of first lane (magic-mul)

            float4 v = *reinterpret_cast<const float4*>(vis + (size_t)b * NC + m);
            float s = aware[b];

            float f0 = v.x, f1 = v.y, f2 = v.z, f3 = v.w;
            unsigned c0 = c;
            unsigned c1 = c + 1u; if (c1 >= (unsigned)C_) c1 -= (unsigned)C_;
            unsigned c2 = c + 2u; if (c2 >= (unsigned)C_) c2 -= (unsigned)C_;
            unsigned c3 = c + 3u; if (c3 >= (unsigned)C_) c3 -= (unsigned)C_;
            if (c0 >= 5u) f0 *= s;
            if (c1 >= 5u) f1 *= s;
            if (c2 >= 5u) f2 *= s;
            if (c3 >= 5u) f3 *= s;

            *reinterpret_cast<float4*>(out + (size_t)b * OUT_IMG + m) =
                make_float4(f0, f1, f2, f3);
        } else {
            // ---- lwir half: straight copy into second N rows of each image ----
            unsigned k  = i - visTasks;
            unsigned b  = k / (unsigned)NC4;
            unsigned m4 = k - b * (unsigned)NC4;
            unsigned m  = m4 * 4u;

            float4 v = *reinterpret_cast<const float4*>(lwir + (size_t)b * NC + m);
            *reinterpret_cast<float4*>(out + (size_t)b * OUT_IMG + NC + m) = v;
        }
    }
}

extern "C" void kernel_launch(void* const* d_in, const int* in_sizes, int n_in,
                              void* d_out, int out_size, void* d_ws, size_t ws_size,
                              hipStream_t stream)
{
    const float* vis   = (const float*)d_in[0];
    const float* lwir  = (const float*)d_in[1];
    const float* aware = (const float*)d_in[2];
    float* out = (float*)d_out;

    const int block = 256;
    // Grid-stride: enough blocks to saturate all 256 CUs with several waves,
    // capped so launch/scheduling overhead stays trivial.
    const int grid = 8192;   // 2M threads, ~16 float4 iterations each

    modal_ense_kernel<<<grid, block, 0, stream>>>(vis, lwir, aware, out);
}

// Round 3
// 174.411 us; speedup vs baseline: 1.2394x; 1.2394x over previous
//
#include <hip/hip_runtime.h>

// Problem constants (from reference): B=32, N=25200, C=85
constexpr int B_  = 32;
constexpr int N_  = 25200;
constexpr int C_  = 85;
constexpr int NC  = N_ * C_;       // 2,142,000 floats per image per modality
constexpr int NC4 = NC / 4;        // 535,500 float4s (divisible: NC % 4 == 0)
constexpr int OUT_IMG4 = 2 * NC4;  // out image stride in float4s

// clang vector type — __builtin_nontemporal_* requires a true vector type,
// not HIP's struct float4.
using f32x4 = float __attribute__((ext_vector_type(4)));

// One float4 per thread. blockIdx.y = batch, blockIdx.z = modality (0=vis, 1=lwir).
// All branches are wave-uniform except the tiny tail guard.
__global__ __launch_bounds__(256) void modal_ense_kernel(
    const f32x4* __restrict__ vis,
    const f32x4* __restrict__ lwir,
    const float* __restrict__ aware,
    f32x4* __restrict__ out)
{
    unsigned m4 = blockIdx.x * 256u + threadIdx.x;
    if (m4 >= (unsigned)NC4) return;
    const unsigned b = blockIdx.y;

    if (blockIdx.z == 0) {
        // visible half: scale class columns (>=5) by aware[b]
        f32x4 v = __builtin_nontemporal_load(&vis[(size_t)b * NC4 + m4]);
        const float s = aware[b];                // uniform -> scalar load
        unsigned c = (m4 * 4u) % (unsigned)C_;   // column of lane's first elem (magic-mod)

        // scale iff column in [5, 84]; c+j <= 88, wrap lands at col <= 3 (<5, unscaled).
        // single unsigned compare: (c+j-5) < 80  <=>  5 <= c+j <= 84
        if (c      - 5u < 80u) v.x *= s;
        if (c + 1u - 5u < 80u) v.y *= s;
        if (c + 2u - 5u < 80u) v.z *= s;
        if (c + 3u - 5u < 80u) v.w *= s;

        __builtin_nontemporal_store(v, &out[(size_t)b * OUT_IMG4 + m4]);
    } else {
        // lwir half: straight streaming copy into second N rows
        f32x4 v = __builtin_nontemporal_load(&lwir[(size_t)b * NC4 + m4]);
        __builtin_nontemporal_store(v, &out[(size_t)b * OUT_IMG4 + NC4 + m4]);
    }
}

extern "C" void kernel_launch(void* const* d_in, const int* in_sizes, int n_in,
                              void* d_out, int out_size, void* d_ws, size_t ws_size,
                              hipStream_t stream)
{
    const f32x4* vis   = (const f32x4*)d_in[0];
    const f32x4* lwir  = (const f32x4*)d_in[1];
    const float* aware = (const float*)d_in[2];
    f32x4* out = (f32x4*)d_out;

    const int block = 256;
    dim3 grid((NC4 + block - 1) / block,  // 2092
              B_,                         // 32
              2);                         // modality

    modal_ense_kernel<<<grid, block, 0, stream>>>(vis, lwir, aware, out);
}